// Round 2
// baseline (1135.871 us; speedup 1.0000x reference)
//
#include <hip/hip_runtime.h>
#include <stdint.h>

typedef unsigned long long u64;
typedef unsigned int u32;

constexpr int Ccand = 32;   // candidates per row
constexpr int Evoc  = 512;  // vocab size
constexpr int Tgt   = 64;   // target_size

// One wave (64 lanes) per row. Lane l owns cols {4l..4l+3} and {256+4l..+3}.
__global__ __launch_bounds__(256, 4) void cooc_expand(
    const int* __restrict__ cand_ids,
    const float* __restrict__ cand_scores,
    const float* __restrict__ cooc,
    float* __restrict__ out_ids,
    float* __restrict__ out_scores,
    int B)
{
    const int lane = threadIdx.x & 63;
    const int wid  = threadIdx.x >> 6;
    const int row  = blockIdx.x * 4 + wid;
    __shared__ u64 selbuf[4][32];
    if (row >= B) return;   // wave-uniform (grid exactly covers B here)

    // ---- load candidates (lanes 0..31) ----
    int   my_id = -1;
    float my_s  = 0.0f;
    if (lane < Ccand) {
        my_id = cand_ids[(size_t)row * Ccand + lane];
        my_s  = cand_scores[(size_t)row * Ccand + lane];
    }

    // ---- duplicate merge, np.add.at order (ascending i, from 0.0) ----
    int   first = 64;
    float sm    = 0.0f;
    #pragma unroll
    for (int j = 0; j < Ccand; ++j) {
        int   idj = __shfl(my_id, j);   // const lane -> v_readlane
        float sj  = __shfl(my_s,  j);
        bool match = (idj == my_id);
        if (match && j < first) first = j;
        sm += match ? sj : 0.0f;
    }
    bool alive = (lane < Ccand) && (first == lane);
    u64 aball = __ballot(alive);
    int m = __popcll(aball);

    // ---- rank alive entries by ascending id (alive ids distinct) ----
    int rk = 0;
    #pragma unroll
    for (int j = 0; j < Ccand; ++j) {
        int idj = __shfl(my_id, j);
        bool aj = (aball >> j) & 1ull;
        rk += (aj && idj < my_id) ? 1 : 0;
    }
    int dst = alive ? rk : ((lane < 32) ? (lane + 32) : lane);
    int sorted_id = __builtin_amdgcn_ds_permute(dst << 2, my_id);
    int sorted_sb = __builtin_amdgcn_ds_permute(dst << 2, __float_as_int(sm));

    // ---- accumulation: fully unrolled, readlane-broadcast ids -> scalar
    // base addresses, all loads independent (compiler pipelines them).
    // t>=m: s forced to 0; fmaf(0, finite, acc)==acc bit-exact (acc>=+0).
    float acc[8] = {0.f,0.f,0.f,0.f,0.f,0.f,0.f,0.f};
    u32 maskbits = 0;
    const int l4 = lane << 2;
    #pragma unroll
    for (int t = 0; t < 32; ++t) {
        int   e  = __shfl(sorted_id, t) & 511;   // clamp: safe addr for t>=m
        float s0 = __int_as_float(__shfl(sorted_sb, t));
        bool live = (t < m);
        float s = live ? s0 : 0.0f;
        const float* rp = cooc + ((size_t)e << 9);
        const float4 a = *reinterpret_cast<const float4*>(rp + l4);
        const float4 b = *reinterpret_cast<const float4*>(rp + 256 + l4);
        acc[0] = fmaf(s, a.x, acc[0]);
        acc[1] = fmaf(s, a.y, acc[1]);
        acc[2] = fmaf(s, a.z, acc[2]);
        acc[3] = fmaf(s, a.w, acc[3]);
        acc[4] = fmaf(s, b.x, acc[4]);
        acc[5] = fmaf(s, b.y, acc[5]);
        acc[6] = fmaf(s, b.z, acc[6]);
        acc[7] = fmaf(s, b.w, acc[7]);
        if (live && (((e & 255) >> 2) == lane))
            maskbits |= 1u << (((e >> 8) << 2) | (e & 3));
    }

    // ---- u64 keys: (f32 bits << 32) | (511 - e); masked -> hi=0 ----
    u64 q[8];
    {
        u32 v;
        v = __float_as_uint(acc[0]); if (maskbits & 1u)   v = 0u; q[0] = ((u64)v << 32) | (u32)(511 - (l4 + 0));
        v = __float_as_uint(acc[1]); if (maskbits & 2u)   v = 0u; q[1] = ((u64)v << 32) | (u32)(511 - (l4 + 1));
        v = __float_as_uint(acc[2]); if (maskbits & 4u)   v = 0u; q[2] = ((u64)v << 32) | (u32)(511 - (l4 + 2));
        v = __float_as_uint(acc[3]); if (maskbits & 8u)   v = 0u; q[3] = ((u64)v << 32) | (u32)(511 - (l4 + 3));
        v = __float_as_uint(acc[4]); if (maskbits & 16u)  v = 0u; q[4] = ((u64)v << 32) | (u32)(511 - (256 + l4 + 0));
        v = __float_as_uint(acc[5]); if (maskbits & 32u)  v = 0u; q[5] = ((u64)v << 32) | (u32)(511 - (256 + l4 + 1));
        v = __float_as_uint(acc[6]); if (maskbits & 64u)  v = 0u; q[6] = ((u64)v << 32) | (u32)(511 - (256 + l4 + 2));
        v = __float_as_uint(acc[7]); if (maskbits & 128u) v = 0u; q[7] = ((u64)v << 32) | (u32)(511 - (256 + l4 + 3));
    }

    // ---- per-lane descending sort of 8 (Batcher odd-even merge sort) ----
    #define CE(a,b) { u64 x_ = q[a], y_ = q[b]; bool g_ = x_ >= y_; q[a] = g_ ? x_ : y_; q[b] = g_ ? y_ : x_; }
    CE(0,1) CE(2,3) CE(4,5) CE(6,7)
    CE(0,2) CE(1,3) CE(4,6) CE(5,7)
    CE(1,2) CE(5,6)
    CE(0,4) CE(1,5) CE(2,6) CE(3,7)
    CE(2,4) CE(3,5)
    CE(1,2) CE(3,4) CE(5,6)
    #undef CE

    // ---- distributed bitonic top-32: keys globally unique, exact ----
    // mirror: combine two sorted runs (half-cleaner, reversed partner regs)
    // xstage: bitonic-merge cross-lane stage; local: distances 4,2,1
    #define MIRROR(XP, S) {                                                  \
        u64 p[8];                                                            \
        _Pragma("unroll") for (int j = 0; j < 8; ++j)                        \
            p[j] = __shfl(q[j], lane ^ (XP));                                \
        bool mx = (lane & (S)) == 0;                                         \
        _Pragma("unroll") for (int j = 0; j < 8; ++j) {                      \
            u64 o = p[7 - j];                                                \
            q[j] = mx ? (q[j] >= o ? q[j] : o) : (q[j] < o ? q[j] : o);      \
        } }
    #define XSTAGE(X) {                                                      \
        u64 p[8];                                                            \
        _Pragma("unroll") for (int j = 0; j < 8; ++j)                        \
            p[j] = __shfl(q[j], lane ^ (X));                                 \
        bool mx = (lane & (X)) == 0;                                         \
        _Pragma("unroll") for (int j = 0; j < 8; ++j)                        \
            q[j] = mx ? (q[j] >= p[j] ? q[j] : p[j])                         \
                      : (q[j] <  p[j] ? q[j] : p[j]);                        \
        }
    #define LOCALM() {                                                      \
        u64 x_, y_;                                                          \
        x_=q[0]; y_=q[4]; q[0]=x_>=y_?x_:y_; q[4]=x_>=y_?y_:x_;              \
        x_=q[1]; y_=q[5]; q[1]=x_>=y_?x_:y_; q[5]=x_>=y_?y_:x_;              \
        x_=q[2]; y_=q[6]; q[2]=x_>=y_?x_:y_; q[6]=x_>=y_?y_:x_;              \
        x_=q[3]; y_=q[7]; q[3]=x_>=y_?x_:y_; q[7]=x_>=y_?y_:x_;              \
        x_=q[0]; y_=q[2]; q[0]=x_>=y_?x_:y_; q[2]=x_>=y_?y_:x_;              \
        x_=q[1]; y_=q[3]; q[1]=x_>=y_?x_:y_; q[3]=x_>=y_?y_:x_;              \
        x_=q[4]; y_=q[6]; q[4]=x_>=y_?x_:y_; q[6]=x_>=y_?y_:x_;              \
        x_=q[5]; y_=q[7]; q[5]=x_>=y_?x_:y_; q[7]=x_>=y_?y_:x_;              \
        x_=q[0]; y_=q[1]; q[0]=x_>=y_?x_:y_; q[1]=x_>=y_?y_:x_;              \
        x_=q[2]; y_=q[3]; q[2]=x_>=y_?x_:y_; q[3]=x_>=y_?y_:x_;              \
        x_=q[4]; y_=q[5]; q[4]=x_>=y_?x_:y_; q[5]=x_>=y_?y_:x_;              \
        x_=q[6]; y_=q[7]; q[6]=x_>=y_?x_:y_; q[7]=x_>=y_?y_:x_;              \
        }

    MIRROR(1, 1)              LOCALM()                      // 8+8   -> 16 over 2 lanes
    MIRROR(3, 2)  XSTAGE(1)   LOCALM()                      // 16+16 -> 32 over 4 lanes
    MIRROR(7, 4)  XSTAGE(2) XSTAGE(1) LOCALM()              // 32+32 -> top32 (prune)
    MIRROR(11, 8) XSTAGE(2) XSTAGE(1) LOCALM()              // top32 of 128
    MIRROR(19,16) XSTAGE(2) XSTAGE(1) LOCALM()              // top32 of 256
    MIRROR(35,32) XSTAGE(2) XSTAGE(1) LOCALM()              // top32 of 512
    #undef MIRROR
    #undef XSTAGE
    #undef LOCALM
    // now lanes 0..3 hold top-32 sorted desc: rank = 8*lane + j

    if (lane < 4) {
        #pragma unroll
        for (int j = 0; j < 8; ++j) selbuf[wid][(lane << 3) | j] = q[j];
    }
    __syncthreads();

    // ---- coalesced stores: [orig 32 | selected 32] ----
    const size_t ob = (size_t)row * Tgt;
    float oid, osc;
    if (lane < Ccand) {
        oid = (float)my_id;
        osc = my_s;
    } else {
        u64 k = selbuf[wid][lane - 32];
        oid = (float)(int)(511 - (u32)(k & 511ull));
        osc = __uint_as_float((u32)(k >> 32));
    }
    out_ids[ob + lane]    = oid;
    out_scores[ob + lane] = osc;
}

extern "C" void kernel_launch(void* const* d_in, const int* in_sizes, int n_in,
                              void* d_out, int out_size, void* d_ws, size_t ws_size,
                              hipStream_t stream) {
    const int*   ids    = (const int*)d_in[0];
    const float* scores = (const float*)d_in[1];
    const float* cooc   = (const float*)d_in[2];
    int B = in_sizes[0] / Ccand;
    float* out_ids    = (float*)d_out;
    float* out_scores = out_ids + (size_t)B * Tgt;
    int blocks = (B + 3) / 4;
    hipLaunchKernelGGL(cooc_expand, dim3(blocks), dim3(256), 0, stream,
                       ids, scores, cooc, out_ids, out_scores, B);
}

// Round 3
// 326.321 us; speedup vs baseline: 3.4808x; 3.4808x over previous
//
#include <hip/hip_runtime.h>
#include <stdint.h>

typedef unsigned long long u64;
typedef unsigned int u32;

constexpr int Ccand = 32;   // candidates per row
constexpr int Evoc  = 512;  // vocab size
constexpr int Tgt   = 64;   // target_size

// One wave (64 lanes) per row. Lane l owns cols {4l..4l+3} and {256+4l..+3}.
__global__ __launch_bounds__(256, 4) void cooc_expand(
    const int* __restrict__ cand_ids,
    const float* __restrict__ cand_scores,
    const float* __restrict__ cooc,
    float* __restrict__ out_ids,
    float* __restrict__ out_scores,
    int B)
{
    const int lane = threadIdx.x & 63;
    const int wid  = threadIdx.x >> 6;
    const int row  = blockIdx.x * 4 + wid;
    __shared__ u64 selbuf[4][32];
    if (row >= B) return;   // wave-uniform (B divisible by 4)

    // ---- load candidates (lanes 0..31) ----
    int   my_id = -1;
    float my_s  = 0.0f;
    if (lane < Ccand) {
        my_id = cand_ids[(size_t)row * Ccand + lane];
        my_s  = cand_scores[(size_t)row * Ccand + lane];
    }

    // ---- duplicate merge, np.add.at order (ascending i, from 0.0) ----
    int   first = 64;
    float sm    = 0.0f;
    #pragma unroll
    for (int j = 0; j < Ccand; ++j) {
        int   idj = __shfl(my_id, j);   // const lane -> readlane
        float sj  = __shfl(my_s,  j);
        bool match = (idj == my_id);
        if (match && j < first) first = j;
        sm += match ? sj : 0.0f;
    }
    bool alive = (lane < Ccand) && (first == lane);
    u64 aball = __ballot(alive);
    int m = __popcll(aball);

    // ---- rank alive entries by ascending id (alive ids distinct) ----
    int rk = 0;
    #pragma unroll
    for (int j = 0; j < Ccand; ++j) {
        int idj = __shfl(my_id, j);
        bool aj = (aball >> j) & 1ull;
        rk += (aj && idj < my_id) ? 1 : 0;
    }
    int dst = alive ? rk : ((lane < 32) ? (lane + 32) : lane);
    int sorted_id = __builtin_amdgcn_ds_permute(dst << 2, my_id);
    int sorted_sb = __builtin_amdgcn_ds_permute(dst << 2, __float_as_int(sm));

    // ---- accumulation: 8 iters x 4 steps; readlane (t uniform) -> SGPR
    // base addr; only 8 float4 live at once (no spill). t>=m: s forced 0,
    // fmaf(0, finite, acc)==acc bit-exact (acc stays >= +0).
    float acc[8] = {0.f,0.f,0.f,0.f,0.f,0.f,0.f,0.f};
    u32 maskbits = 0;
    const int l4 = lane << 2;
    #pragma unroll 1
    for (int t = 0; t < 32; t += 4) {
        int e0 = __builtin_amdgcn_readlane(sorted_id, t + 0) & 511;
        int e1 = __builtin_amdgcn_readlane(sorted_id, t + 1) & 511;
        int e2 = __builtin_amdgcn_readlane(sorted_id, t + 2) & 511;
        int e3 = __builtin_amdgcn_readlane(sorted_id, t + 3) & 511;
        float s0 = (t + 0 < m) ? __int_as_float(__builtin_amdgcn_readlane(sorted_sb, t + 0)) : 0.0f;
        float s1 = (t + 1 < m) ? __int_as_float(__builtin_amdgcn_readlane(sorted_sb, t + 1)) : 0.0f;
        float s2 = (t + 2 < m) ? __int_as_float(__builtin_amdgcn_readlane(sorted_sb, t + 2)) : 0.0f;
        float s3 = (t + 3 < m) ? __int_as_float(__builtin_amdgcn_readlane(sorted_sb, t + 3)) : 0.0f;
        const float* r0 = cooc + ((size_t)e0 << 9);
        const float* r1 = cooc + ((size_t)e1 << 9);
        const float* r2 = cooc + ((size_t)e2 << 9);
        const float* r3 = cooc + ((size_t)e3 << 9);
        float4 a0 = *reinterpret_cast<const float4*>(r0 + l4);
        float4 b0 = *reinterpret_cast<const float4*>(r0 + 256 + l4);
        float4 a1 = *reinterpret_cast<const float4*>(r1 + l4);
        float4 b1 = *reinterpret_cast<const float4*>(r1 + 256 + l4);
        float4 a2 = *reinterpret_cast<const float4*>(r2 + l4);
        float4 b2 = *reinterpret_cast<const float4*>(r2 + 256 + l4);
        float4 a3 = *reinterpret_cast<const float4*>(r3 + l4);
        float4 b3 = *reinterpret_cast<const float4*>(r3 + 256 + l4);
        acc[0] = fmaf(s0, a0.x, acc[0]); acc[1] = fmaf(s0, a0.y, acc[1]);
        acc[2] = fmaf(s0, a0.z, acc[2]); acc[3] = fmaf(s0, a0.w, acc[3]);
        acc[4] = fmaf(s0, b0.x, acc[4]); acc[5] = fmaf(s0, b0.y, acc[5]);
        acc[6] = fmaf(s0, b0.z, acc[6]); acc[7] = fmaf(s0, b0.w, acc[7]);
        acc[0] = fmaf(s1, a1.x, acc[0]); acc[1] = fmaf(s1, a1.y, acc[1]);
        acc[2] = fmaf(s1, a1.z, acc[2]); acc[3] = fmaf(s1, a1.w, acc[3]);
        acc[4] = fmaf(s1, b1.x, acc[4]); acc[5] = fmaf(s1, b1.y, acc[5]);
        acc[6] = fmaf(s1, b1.z, acc[6]); acc[7] = fmaf(s1, b1.w, acc[7]);
        acc[0] = fmaf(s2, a2.x, acc[0]); acc[1] = fmaf(s2, a2.y, acc[1]);
        acc[2] = fmaf(s2, a2.z, acc[2]); acc[3] = fmaf(s2, a2.w, acc[3]);
        acc[4] = fmaf(s2, b2.x, acc[4]); acc[5] = fmaf(s2, b2.y, acc[5]);
        acc[6] = fmaf(s2, b2.z, acc[6]); acc[7] = fmaf(s2, b2.w, acc[7]);
        acc[0] = fmaf(s3, a3.x, acc[0]); acc[1] = fmaf(s3, a3.y, acc[1]);
        acc[2] = fmaf(s3, a3.z, acc[2]); acc[3] = fmaf(s3, a3.w, acc[3]);
        acc[4] = fmaf(s3, b3.x, acc[4]); acc[5] = fmaf(s3, b3.y, acc[5]);
        acc[6] = fmaf(s3, b3.z, acc[6]); acc[7] = fmaf(s3, b3.w, acc[7]);
        // masked-slot bookkeeping (reference: cooc_scores[b, e] = -inf)
        if ((t + 0 < m) && (((e0 & 255) >> 2) == lane)) maskbits |= 1u << (((e0 >> 8) << 2) | (e0 & 3));
        if ((t + 1 < m) && (((e1 & 255) >> 2) == lane)) maskbits |= 1u << (((e1 >> 8) << 2) | (e1 & 3));
        if ((t + 2 < m) && (((e2 & 255) >> 2) == lane)) maskbits |= 1u << (((e2 >> 8) << 2) | (e2 & 3));
        if ((t + 3 < m) && (((e3 & 255) >> 2) == lane)) maskbits |= 1u << (((e3 >> 8) << 2) | (e3 & 3));
    }

    // ---- u64 keys: (f32 bits << 32) | (511 - e); masked -> hi=0 ----
    u64 q[8];
    {
        u32 v;
        v = __float_as_uint(acc[0]); if (maskbits & 1u)   v = 0u; q[0] = ((u64)v << 32) | (u32)(511 - (l4 + 0));
        v = __float_as_uint(acc[1]); if (maskbits & 2u)   v = 0u; q[1] = ((u64)v << 32) | (u32)(511 - (l4 + 1));
        v = __float_as_uint(acc[2]); if (maskbits & 4u)   v = 0u; q[2] = ((u64)v << 32) | (u32)(511 - (l4 + 2));
        v = __float_as_uint(acc[3]); if (maskbits & 8u)   v = 0u; q[3] = ((u64)v << 32) | (u32)(511 - (l4 + 3));
        v = __float_as_uint(acc[4]); if (maskbits & 16u)  v = 0u; q[4] = ((u64)v << 32) | (u32)(511 - (256 + l4 + 0));
        v = __float_as_uint(acc[5]); if (maskbits & 32u)  v = 0u; q[5] = ((u64)v << 32) | (u32)(511 - (256 + l4 + 1));
        v = __float_as_uint(acc[6]); if (maskbits & 64u)  v = 0u; q[6] = ((u64)v << 32) | (u32)(511 - (256 + l4 + 2));
        v = __float_as_uint(acc[7]); if (maskbits & 128u) v = 0u; q[7] = ((u64)v << 32) | (u32)(511 - (256 + l4 + 3));
    }

    // ---- per-lane descending sort of 8 (Batcher odd-even merge sort) ----
    #define CE(a,b) { u64 x_ = q[a], y_ = q[b]; bool g_ = x_ >= y_; q[a] = g_ ? x_ : y_; q[b] = g_ ? y_ : x_; }
    CE(0,1) CE(2,3) CE(4,5) CE(6,7)
    CE(0,2) CE(1,3) CE(4,6) CE(5,7)
    CE(1,2) CE(5,6)
    CE(0,4) CE(1,5) CE(2,6) CE(3,7)
    CE(2,4) CE(3,5)
    CE(1,2) CE(3,4) CE(5,6)
    #undef CE

    // ---- distributed bitonic top-32 (exact; keys globally unique) ----
    #define MIRROR(XP, S) {                                                  \
        u64 p[8];                                                            \
        _Pragma("unroll") for (int j = 0; j < 8; ++j)                        \
            p[j] = __shfl(q[j], lane ^ (XP));                                \
        bool mx = (lane & (S)) == 0;                                         \
        _Pragma("unroll") for (int j = 0; j < 8; ++j) {                      \
            u64 o = p[7 - j];                                                \
            q[j] = mx ? (q[j] >= o ? q[j] : o) : (q[j] < o ? q[j] : o);      \
        } }
    #define XSTAGE(X) {                                                      \
        u64 p[8];                                                            \
        _Pragma("unroll") for (int j = 0; j < 8; ++j)                        \
            p[j] = __shfl(q[j], lane ^ (X));                                 \
        bool mx = (lane & (X)) == 0;                                         \
        _Pragma("unroll") for (int j = 0; j < 8; ++j)                        \
            q[j] = mx ? (q[j] >= p[j] ? q[j] : p[j])                         \
                      : (q[j] <  p[j] ? q[j] : p[j]);                        \
        }
    #define LOCALM() {                                                      \
        u64 x_, y_;                                                          \
        x_=q[0]; y_=q[4]; q[0]=x_>=y_?x_:y_; q[4]=x_>=y_?y_:x_;              \
        x_=q[1]; y_=q[5]; q[1]=x_>=y_?x_:y_; q[5]=x_>=y_?y_:x_;              \
        x_=q[2]; y_=q[6]; q[2]=x_>=y_?x_:y_; q[6]=x_>=y_?y_:x_;              \
        x_=q[3]; y_=q[7]; q[3]=x_>=y_?x_:y_; q[7]=x_>=y_?y_:x_;              \
        x_=q[0]; y_=q[2]; q[0]=x_>=y_?x_:y_; q[2]=x_>=y_?y_:x_;              \
        x_=q[1]; y_=q[3]; q[1]=x_>=y_?x_:y_; q[3]=x_>=y_?y_:x_;              \
        x_=q[4]; y_=q[6]; q[4]=x_>=y_?x_:y_; q[6]=x_>=y_?y_:x_;              \
        x_=q[5]; y_=q[7]; q[5]=x_>=y_?x_:y_; q[7]=x_>=y_?y_:x_;              \
        x_=q[0]; y_=q[1]; q[0]=x_>=y_?x_:y_; q[1]=x_>=y_?y_:x_;              \
        x_=q[2]; y_=q[3]; q[2]=x_>=y_?x_:y_; q[3]=x_>=y_?y_:x_;              \
        x_=q[4]; y_=q[5]; q[4]=x_>=y_?x_:y_; q[5]=x_>=y_?y_:x_;              \
        x_=q[6]; y_=q[7]; q[6]=x_>=y_?x_:y_; q[7]=x_>=y_?y_:x_;              \
        }

    MIRROR(1, 1)              LOCALM()                      // 8+8   -> 16 over 2 lanes
    MIRROR(3, 2)  XSTAGE(1)   LOCALM()                      // 16+16 -> 32 over 4 lanes
    MIRROR(7, 4)  XSTAGE(2) XSTAGE(1) LOCALM()              // 32+32 -> top32 (prune)
    MIRROR(11, 8) XSTAGE(2) XSTAGE(1) LOCALM()              // top32 of 128
    MIRROR(19,16) XSTAGE(2) XSTAGE(1) LOCALM()              // top32 of 256
    MIRROR(35,32) XSTAGE(2) XSTAGE(1) LOCALM()              // top32 of 512
    #undef MIRROR
    #undef XSTAGE
    #undef LOCALM
    // lanes 0..3 hold top-32 sorted desc: rank = 8*lane + j

    if (lane < 4) {
        #pragma unroll
        for (int j = 0; j < 8; ++j) selbuf[wid][(lane << 3) | j] = q[j];
    }
    __syncthreads();

    // ---- coalesced stores: [orig 32 | selected 32] ----
    const size_t ob = (size_t)row * Tgt;
    float oid, osc;
    if (lane < Ccand) {
        oid = (float)my_id;
        osc = my_s;
    } else {
        u64 k = selbuf[wid][lane - 32];
        oid = (float)(int)(511 - (u32)(k & 511ull));
        osc = __uint_as_float((u32)(k >> 32));
    }
    out_ids[ob + lane]    = oid;
    out_scores[ob + lane] = osc;
}

extern "C" void kernel_launch(void* const* d_in, const int* in_sizes, int n_in,
                              void* d_out, int out_size, void* d_ws, size_t ws_size,
                              hipStream_t stream) {
    const int*   ids    = (const int*)d_in[0];
    const float* scores = (const float*)d_in[1];
    const float* cooc   = (const float*)d_in[2];
    int B = in_sizes[0] / Ccand;
    float* out_ids    = (float*)d_out;
    float* out_scores = out_ids + (size_t)B * Tgt;
    int blocks = (B + 3) / 4;
    hipLaunchKernelGGL(cooc_expand, dim3(blocks), dim3(256), 0, stream,
                       ids, scores, cooc, out_ids, out_scores, B);
}

// Round 4
// 261.547 us; speedup vs baseline: 4.3429x; 1.2477x over previous
//
#include <hip/hip_runtime.h>
#include <stdint.h>

typedef unsigned long long u64;
typedef unsigned int u32;

constexpr int Ccand = 32;   // candidates per row
constexpr int Evoc  = 512;  // vocab size
constexpr int Tgt   = 64;   // target_size

// One wave (64 lanes) per row. Lane l owns cols {4l..4l+3} and {256+4l..+3}.
__global__ __launch_bounds__(256, 4) void cooc_expand(
    const int* __restrict__ cand_ids,
    const float* __restrict__ cand_scores,
    const float* __restrict__ cooc,
    float* __restrict__ out_ids,
    float* __restrict__ out_scores,
    int B)
{
    const int lane = threadIdx.x & 63;
    const int wid  = threadIdx.x >> 6;
    const int row  = blockIdx.x * 4 + wid;
    __shared__ u64 selbuf[4][32];
    if (row >= B) return;   // never taken (B % 4 == 0, exact grid) — barrier safe

    // ---- load candidates (lanes 0..31) ----
    int   my_id = -1;
    float my_s  = 0.0f;
    if (lane < Ccand) {
        my_id = cand_ids[(size_t)row * Ccand + lane];
        my_s  = cand_scores[(size_t)row * Ccand + lane];
    }

    // ---- duplicate merge, np.add.at order (ascending i, from 0.0) ----
    int   first = 64;
    float sm    = 0.0f;
    #pragma unroll
    for (int j = 0; j < Ccand; ++j) {
        int   idj = __shfl(my_id, j);   // const lane -> readlane
        float sj  = __shfl(my_s,  j);
        bool match = (idj == my_id);
        if (match && j < first) first = j;
        sm += match ? sj : 0.0f;
    }
    bool alive = (lane < Ccand) && (first == lane);
    u64 aball = __ballot(alive);
    int m = __popcll(aball);

    // ---- rank alive entries by ascending id (alive ids distinct) ----
    int rk = 0;
    #pragma unroll
    for (int j = 0; j < Ccand; ++j) {
        int idj = __shfl(my_id, j);
        bool aj = (aball >> j) & 1ull;
        rk += (aj && idj < my_id) ? 1 : 0;
    }
    int dst = alive ? rk : ((lane < 32) ? (lane + 32) : lane);
    int sorted_id = __builtin_amdgcn_ds_permute(dst << 2, my_id);
    int sorted_sb = __builtin_amdgcn_ds_permute(dst << 2, __float_as_int(sm));

    // ---- accumulation: 8 iters x 4 steps; readlane -> SGPR base addr;
    // only 8 float4 live at once. t>=m: s=0, fmaf(0,·,acc)==acc bit-exact.
    float acc[8] = {0.f,0.f,0.f,0.f,0.f,0.f,0.f,0.f};
    u32 maskbits = 0;
    const int l4 = lane << 2;
    #pragma unroll 1
    for (int t = 0; t < 32; t += 4) {
        int e0 = __builtin_amdgcn_readlane(sorted_id, t + 0) & 511;
        int e1 = __builtin_amdgcn_readlane(sorted_id, t + 1) & 511;
        int e2 = __builtin_amdgcn_readlane(sorted_id, t + 2) & 511;
        int e3 = __builtin_amdgcn_readlane(sorted_id, t + 3) & 511;
        float s0 = (t + 0 < m) ? __int_as_float(__builtin_amdgcn_readlane(sorted_sb, t + 0)) : 0.0f;
        float s1 = (t + 1 < m) ? __int_as_float(__builtin_amdgcn_readlane(sorted_sb, t + 1)) : 0.0f;
        float s2 = (t + 2 < m) ? __int_as_float(__builtin_amdgcn_readlane(sorted_sb, t + 2)) : 0.0f;
        float s3 = (t + 3 < m) ? __int_as_float(__builtin_amdgcn_readlane(sorted_sb, t + 3)) : 0.0f;
        const float* r0 = cooc + ((size_t)e0 << 9);
        const float* r1 = cooc + ((size_t)e1 << 9);
        const float* r2 = cooc + ((size_t)e2 << 9);
        const float* r3 = cooc + ((size_t)e3 << 9);
        float4 a0 = *reinterpret_cast<const float4*>(r0 + l4);
        float4 b0 = *reinterpret_cast<const float4*>(r0 + 256 + l4);
        float4 a1 = *reinterpret_cast<const float4*>(r1 + l4);
        float4 b1 = *reinterpret_cast<const float4*>(r1 + 256 + l4);
        float4 a2 = *reinterpret_cast<const float4*>(r2 + l4);
        float4 b2 = *reinterpret_cast<const float4*>(r2 + 256 + l4);
        float4 a3 = *reinterpret_cast<const float4*>(r3 + l4);
        float4 b3 = *reinterpret_cast<const float4*>(r3 + 256 + l4);
        acc[0] = fmaf(s0, a0.x, acc[0]); acc[1] = fmaf(s0, a0.y, acc[1]);
        acc[2] = fmaf(s0, a0.z, acc[2]); acc[3] = fmaf(s0, a0.w, acc[3]);
        acc[4] = fmaf(s0, b0.x, acc[4]); acc[5] = fmaf(s0, b0.y, acc[5]);
        acc[6] = fmaf(s0, b0.z, acc[6]); acc[7] = fmaf(s0, b0.w, acc[7]);
        acc[0] = fmaf(s1, a1.x, acc[0]); acc[1] = fmaf(s1, a1.y, acc[1]);
        acc[2] = fmaf(s1, a1.z, acc[2]); acc[3] = fmaf(s1, a1.w, acc[3]);
        acc[4] = fmaf(s1, b1.x, acc[4]); acc[5] = fmaf(s1, b1.y, acc[5]);
        acc[6] = fmaf(s1, b1.z, acc[6]); acc[7] = fmaf(s1, b1.w, acc[7]);
        acc[0] = fmaf(s2, a2.x, acc[0]); acc[1] = fmaf(s2, a2.y, acc[1]);
        acc[2] = fmaf(s2, a2.z, acc[2]); acc[3] = fmaf(s2, a2.w, acc[3]);
        acc[4] = fmaf(s2, b2.x, acc[4]); acc[5] = fmaf(s2, b2.y, acc[5]);
        acc[6] = fmaf(s2, b2.z, acc[6]); acc[7] = fmaf(s2, b2.w, acc[7]);
        acc[0] = fmaf(s3, a3.x, acc[0]); acc[1] = fmaf(s3, a3.y, acc[1]);
        acc[2] = fmaf(s3, a3.z, acc[2]); acc[3] = fmaf(s3, a3.w, acc[3]);
        acc[4] = fmaf(s3, b3.x, acc[4]); acc[5] = fmaf(s3, b3.y, acc[5]);
        acc[6] = fmaf(s3, b3.z, acc[6]); acc[7] = fmaf(s3, b3.w, acc[7]);
        if ((t + 0 < m) && (((e0 & 255) >> 2) == lane)) maskbits |= 1u << (((e0 >> 8) << 2) | (e0 & 3));
        if ((t + 1 < m) && (((e1 & 255) >> 2) == lane)) maskbits |= 1u << (((e1 >> 8) << 2) | (e1 & 3));
        if ((t + 2 < m) && (((e2 & 255) >> 2) == lane)) maskbits |= 1u << (((e2 >> 8) << 2) | (e2 & 3));
        if ((t + 3 < m) && (((e3 & 255) >> 2) == lane)) maskbits |= 1u << (((e3 >> 8) << 2) | (e3 & 3));
    }

    // ---- original-layout values; masked -> -1.0 (strictly below all) ----
    float v[8];
    #pragma unroll
    for (int j = 0; j < 8; ++j)
        v[j] = ((maskbits >> j) & 1u) ? -1.0f : acc[j];

    // ---- f32 value-only network: per-lane sort8 desc + merge/prune ----
    float q[8];
    #pragma unroll
    for (int j = 0; j < 8; ++j) q[j] = v[j];

    #define CEF(a,b) { float h_ = fmaxf(q[a], q[b]); float l_ = fminf(q[a], q[b]); q[a] = h_; q[b] = l_; }
    CEF(0,1) CEF(2,3) CEF(4,5) CEF(6,7)
    CEF(0,2) CEF(1,3) CEF(4,6) CEF(5,7)
    CEF(1,2) CEF(5,6)
    CEF(0,4) CEF(1,5) CEF(2,6) CEF(3,7)
    CEF(2,4) CEF(3,5)
    CEF(1,2) CEF(3,4) CEF(5,6)

    #define MIRRORF(XP, S) {                                                 \
        float p_[8];                                                         \
        _Pragma("unroll") for (int j = 0; j < 8; ++j)                        \
            p_[j] = __shfl(q[j], lane ^ (XP));                               \
        bool mx = (lane & (S)) == 0;                                         \
        _Pragma("unroll") for (int j = 0; j < 8; ++j) {                      \
            float o = p_[7 - j];                                             \
            q[j] = mx ? fmaxf(q[j], o) : fminf(q[j], o);                     \
        } }
    #define XSTAGEF(X) {                                                     \
        float p_[8];                                                         \
        _Pragma("unroll") for (int j = 0; j < 8; ++j)                        \
            p_[j] = __shfl(q[j], lane ^ (X));                                \
        bool mx = (lane & (X)) == 0;                                         \
        _Pragma("unroll") for (int j = 0; j < 8; ++j)                        \
            q[j] = mx ? fmaxf(q[j], p_[j]) : fminf(q[j], p_[j]);             \
        }
    #define LOCALMF() {                                                     \
        CEF(0,4) CEF(1,5) CEF(2,6) CEF(3,7)                                  \
        CEF(0,2) CEF(1,3) CEF(4,6) CEF(5,7)                                  \
        CEF(0,1) CEF(2,3) CEF(4,5) CEF(6,7)                                  \
        }

    MIRRORF(1, 1)                 LOCALMF()               // 8+8   -> 16
    MIRRORF(3, 2)  XSTAGEF(1)     LOCALMF()               // 16+16 -> 32
    MIRRORF(7, 4)  XSTAGEF(2) XSTAGEF(1) LOCALMF()        // prune 64 -> 32
    MIRRORF(11, 8) XSTAGEF(2) XSTAGEF(1) LOCALMF()        // prune 128
    MIRRORF(19,16) XSTAGEF(2) XSTAGEF(1) LOCALMF()        // prune 256
    MIRRORF(35,32) XSTAGEF(2) XSTAGEF(1) LOCALMF()        // prune 512
    #undef MIRRORF
    #undef XSTAGEF
    #undef LOCALMF
    #undef CEF
    // lanes 0..3 hold the exact top-32 VALUE multiset, sorted desc.

    // ---- exact threshold T (32nd largest) and need = #(==T) in top-32 ----
    float T = __shfl(q[7], 3);
    int need = 0;
    #pragma unroll
    for (int j = 0; j < 8; ++j) {
        u64 b = __ballot((lane < 4) && (q[j] == T));
        need += __popcll(b);
    }

    // ---- exact membership: v>T always in; among v==T, lowest `need`
    // global column indices (np tie-break). Column order: regs 0..3 are
    // cols 4*lane+j (all < 256), regs 4..7 are cols 256+4*lane+(j-4).
    int eq[8], gt[8];
    #pragma unroll
    for (int j = 0; j < 8; ++j) { eq[j] = (v[j] == T) ? 1 : 0; gt[j] = (v[j] > T) ? 1 : 0; }
    int eqlo = eq[0] + eq[1] + eq[2] + eq[3];
    int eqhi = eq[4] + eq[5] + eq[6] + eq[7];
    u32 packed = (u32)eqlo | ((u32)eqhi << 16);
    u32 incl = packed;
    #pragma unroll
    for (int i = 1; i < 64; i <<= 1) {
        u32 t2 = __shfl_up(incl, i);
        if (lane >= i) incl += t2;
    }
    u32 excl = incl - packed;
    u32 totlo = __shfl(incl, 63) & 0xffffu;
    int base_lo = (int)(excl & 0xffffu);
    int base_hi = (int)totlo + (int)(excl >> 16);
    int idxrank[8];
    idxrank[0] = base_lo;
    idxrank[1] = base_lo + eq[0];
    idxrank[2] = base_lo + eq[0] + eq[1];
    idxrank[3] = base_lo + eq[0] + eq[1] + eq[2];
    idxrank[4] = base_hi;
    idxrank[5] = base_hi + eq[4];
    idxrank[6] = base_hi + eq[4] + eq[5];
    idxrank[7] = base_hi + eq[4] + eq[5] + eq[6];
    int sel[8];
    #pragma unroll
    for (int j = 0; j < 8; ++j)
        sel[j] = gt[j] | (eq[j] & ((idxrank[j] < need) ? 1 : 0));

    // ---- scatter the exactly-32 selected u64 keys to LDS slots ----
    int sc = sel[0] + sel[1] + sel[2] + sel[3] + sel[4] + sel[5] + sel[6] + sel[7];
    u32 sincl = (u32)sc;
    #pragma unroll
    for (int i = 1; i < 64; i <<= 1) {
        u32 t2 = __shfl_up(sincl, i);
        if (lane >= i) sincl += t2;
    }
    int sbase = (int)sincl - sc;
    int slot = sbase;
    #pragma unroll
    for (int j = 0; j < 8; ++j) {
        if (sel[j]) {
            int col = (j < 4) ? (l4 + j) : (256 + l4 + (j - 4));
            u64 key = ((u64)__float_as_uint(v[j]) << 32) | (u32)(511 - col);
            selbuf[wid][slot] = key;
        }
        slot += sel[j];
    }
    __syncthreads();

    // ---- 32-wide bitonic sort (1 key/lane) desc by (value, col asc) ----
    // upper half mirrors lower (same data, lane&31 directions) so lane 32+t
    // ends holding rank t directly. Keys are unique (distinct cols).
    u64 k = selbuf[wid][lane & 31];
    const int lane31 = lane & 31;
    #pragma unroll
    for (int k2 = 2; k2 <= 32; k2 <<= 1) {
        #pragma unroll
        for (int j = k2 >> 1; j > 0; j >>= 1) {
            u64 o = __shfl_xor(k, j);
            bool lower = (lane31 & j) == 0;
            bool keepMax = ((lane31 & k2) == 0) ? lower : !lower;
            bool g = k > o;
            k = (keepMax == g) ? k : o;
        }
    }

    // ---- coalesced stores: [orig 32 | selected 32] ----
    const size_t ob = (size_t)row * Tgt;
    float oid, osc;
    if (lane < Ccand) {
        oid = (float)my_id;
        osc = my_s;
    } else {
        oid = (float)(int)(511 - (u32)(k & 511ull));
        osc = __uint_as_float((u32)(k >> 32));
    }
    out_ids[ob + lane]    = oid;
    out_scores[ob + lane] = osc;
}

extern "C" void kernel_launch(void* const* d_in, const int* in_sizes, int n_in,
                              void* d_out, int out_size, void* d_ws, size_t ws_size,
                              hipStream_t stream) {
    const int*   ids    = (const int*)d_in[0];
    const float* scores = (const float*)d_in[1];
    const float* cooc   = (const float*)d_in[2];
    int B = in_sizes[0] / Ccand;
    float* out_ids    = (float*)d_out;
    float* out_scores = out_ids + (size_t)B * Tgt;
    int blocks = (B + 3) / 4;
    hipLaunchKernelGGL(cooc_expand, dim3(blocks), dim3(256), 0, stream,
                       ids, scores, cooc, out_ids, out_scores, B);
}

// Round 5
// 214.075 us; speedup vs baseline: 5.3059x; 1.2218x over previous
//
#include <hip/hip_runtime.h>
#include <stdint.h>

typedef unsigned long long u64;
typedef unsigned int u32;

constexpr int Ccand = 32;   // candidates per row
constexpr int Evoc  = 512;  // vocab size
constexpr int Tgt   = 64;   // target_size

// descending bitonic sort of one f32 per lane across the 64-lane wave
__device__ __forceinline__ void sort64_desc_f32(float& a, int lane) {
    #pragma unroll
    for (int k2 = 2; k2 <= 64; k2 <<= 1) {
        #pragma unroll
        for (int j = k2 >> 1; j > 0; j >>= 1) {
            float o = __shfl_xor(a, j);
            bool lower = (lane & j) == 0;
            bool keepMax = ((lane & k2) == 0) ? lower : !lower;
            bool g = a > o;
            a = (keepMax == g) ? a : o;
        }
    }
}

// descending bitonic sort of one u64 key per lane across the wave
__device__ __forceinline__ void sort64_desc_u64(u64& a, int lane) {
    #pragma unroll
    for (int k2 = 2; k2 <= 64; k2 <<= 1) {
        #pragma unroll
        for (int j = k2 >> 1; j > 0; j >>= 1) {
            u64 o = __shfl_xor(a, j);
            bool lower = (lane & j) == 0;
            bool keepMax = ((lane & k2) == 0) ? lower : !lower;
            bool g = a > o;
            a = (keepMax == g) ? a : o;
        }
    }
}

// One wave (64 lanes) per row. Lane l owns cols {4l..4l+3} and {256+4l..+3}.
__global__ __launch_bounds__(256, 4) void cooc_expand(
    const int* __restrict__ cand_ids,
    const float* __restrict__ cand_scores,
    const float* __restrict__ cooc,
    float* __restrict__ out_ids,
    float* __restrict__ out_scores,
    int B)
{
    const int lane = threadIdx.x & 63;
    const int wid  = threadIdx.x >> 6;
    const int row  = blockIdx.x * 4 + wid;
    __shared__ u64 buf[4][512];   // per-wave survivor buffer (worst case 512)
    if (row >= B) return;   // never taken (B % 4 == 0); no block barriers used

    // ---- load candidates (lanes 0..31) ----
    int   my_id = -1;
    float my_s  = 0.0f;
    if (lane < Ccand) {
        my_id = cand_ids[(size_t)row * Ccand + lane];
        my_s  = cand_scores[(size_t)row * Ccand + lane];
    }

    // ---- duplicate merge, np.add.at order (ascending i, from 0.0) ----
    int   first = 64;
    float sm    = 0.0f;
    #pragma unroll
    for (int j = 0; j < Ccand; ++j) {
        int   idj = __shfl(my_id, j);   // const lane -> readlane
        float sj  = __shfl(my_s,  j);
        bool match = (idj == my_id);
        if (match && j < first) first = j;
        sm += match ? sj : 0.0f;
    }
    bool alive = (lane < Ccand) && (first == lane);
    u64 aball = __ballot(alive);
    int m = __popcll(aball);

    // ---- rank alive entries by ascending id (alive ids distinct) ----
    int rk = 0;
    #pragma unroll
    for (int j = 0; j < Ccand; ++j) {
        int idj = __shfl(my_id, j);
        bool aj = (aball >> j) & 1ull;
        rk += (aj && idj < my_id) ? 1 : 0;
    }
    int dst = alive ? rk : ((lane < 32) ? (lane + 32) : lane);
    int sorted_id = __builtin_amdgcn_ds_permute(dst << 2, my_id);
    int sorted_sb = __builtin_amdgcn_ds_permute(dst << 2, __float_as_int(sm));

    // ---- accumulation: 8 iters x 4 steps; readlane -> SGPR base addr;
    // only 8 float4 live at once. t>=m: s=0, fmaf(0,·,acc)==acc bit-exact.
    float acc[8] = {0.f,0.f,0.f,0.f,0.f,0.f,0.f,0.f};
    u32 maskbits = 0;
    const int l4 = lane << 2;
    #pragma unroll 1
    for (int t = 0; t < 32; t += 4) {
        int e0 = __builtin_amdgcn_readlane(sorted_id, t + 0) & 511;
        int e1 = __builtin_amdgcn_readlane(sorted_id, t + 1) & 511;
        int e2 = __builtin_amdgcn_readlane(sorted_id, t + 2) & 511;
        int e3 = __builtin_amdgcn_readlane(sorted_id, t + 3) & 511;
        float s0 = (t + 0 < m) ? __int_as_float(__builtin_amdgcn_readlane(sorted_sb, t + 0)) : 0.0f;
        float s1 = (t + 1 < m) ? __int_as_float(__builtin_amdgcn_readlane(sorted_sb, t + 1)) : 0.0f;
        float s2 = (t + 2 < m) ? __int_as_float(__builtin_amdgcn_readlane(sorted_sb, t + 2)) : 0.0f;
        float s3 = (t + 3 < m) ? __int_as_float(__builtin_amdgcn_readlane(sorted_sb, t + 3)) : 0.0f;
        const float* r0 = cooc + ((size_t)e0 << 9);
        const float* r1 = cooc + ((size_t)e1 << 9);
        const float* r2 = cooc + ((size_t)e2 << 9);
        const float* r3 = cooc + ((size_t)e3 << 9);
        float4 a0 = *reinterpret_cast<const float4*>(r0 + l4);
        float4 b0 = *reinterpret_cast<const float4*>(r0 + 256 + l4);
        float4 a1 = *reinterpret_cast<const float4*>(r1 + l4);
        float4 b1 = *reinterpret_cast<const float4*>(r1 + 256 + l4);
        float4 a2 = *reinterpret_cast<const float4*>(r2 + l4);
        float4 b2 = *reinterpret_cast<const float4*>(r2 + 256 + l4);
        float4 a3 = *reinterpret_cast<const float4*>(r3 + l4);
        float4 b3 = *reinterpret_cast<const float4*>(r3 + 256 + l4);
        acc[0] = fmaf(s0, a0.x, acc[0]); acc[1] = fmaf(s0, a0.y, acc[1]);
        acc[2] = fmaf(s0, a0.z, acc[2]); acc[3] = fmaf(s0, a0.w, acc[3]);
        acc[4] = fmaf(s0, b0.x, acc[4]); acc[5] = fmaf(s0, b0.y, acc[5]);
        acc[6] = fmaf(s0, b0.z, acc[6]); acc[7] = fmaf(s0, b0.w, acc[7]);
        acc[0] = fmaf(s1, a1.x, acc[0]); acc[1] = fmaf(s1, a1.y, acc[1]);
        acc[2] = fmaf(s1, a1.z, acc[2]); acc[3] = fmaf(s1, a1.w, acc[3]);
        acc[4] = fmaf(s1, b1.x, acc[4]); acc[5] = fmaf(s1, b1.y, acc[5]);
        acc[6] = fmaf(s1, b1.z, acc[6]); acc[7] = fmaf(s1, b1.w, acc[7]);
        acc[0] = fmaf(s2, a2.x, acc[0]); acc[1] = fmaf(s2, a2.y, acc[1]);
        acc[2] = fmaf(s2, a2.z, acc[2]); acc[3] = fmaf(s2, a2.w, acc[3]);
        acc[4] = fmaf(s2, b2.x, acc[4]); acc[5] = fmaf(s2, b2.y, acc[5]);
        acc[6] = fmaf(s2, b2.z, acc[6]); acc[7] = fmaf(s2, b2.w, acc[7]);
        acc[0] = fmaf(s3, a3.x, acc[0]); acc[1] = fmaf(s3, a3.y, acc[1]);
        acc[2] = fmaf(s3, a3.z, acc[2]); acc[3] = fmaf(s3, a3.w, acc[3]);
        acc[4] = fmaf(s3, b3.x, acc[4]); acc[5] = fmaf(s3, b3.y, acc[5]);
        acc[6] = fmaf(s3, b3.z, acc[6]); acc[7] = fmaf(s3, b3.w, acc[7]);
        if ((t + 0 < m) && (((e0 & 255) >> 2) == lane)) maskbits |= 1u << (((e0 >> 8) << 2) | (e0 & 3));
        if ((t + 1 < m) && (((e1 & 255) >> 2) == lane)) maskbits |= 1u << (((e1 >> 8) << 2) | (e1 & 3));
        if ((t + 2 < m) && (((e2 & 255) >> 2) == lane)) maskbits |= 1u << (((e2 >> 8) << 2) | (e2 & 3));
        if ((t + 3 < m) && (((e3 & 255) >> 2) == lane)) maskbits |= 1u << (((e3 >> 8) << 2) | (e3 & 3));
    }

    // ---- original-layout values; masked -> -1.0 (strictly below all) ----
    float v[8];
    #pragma unroll
    for (int j = 0; j < 8; ++j)
        v[j] = ((maskbits >> j) & 1u) ? -1.0f : acc[j];

    // ---- L32: 32nd largest of per-lane maxima. Guarantee: >=32 values
    // (the 32 top lanes' maxima) are >= L32, hence T(true 32nd) >= L32 and
    // every top-32 element (incl. all ==T ties) has v >= L32.
    float mx8 = v[0];
    #pragma unroll
    for (int j = 1; j < 8; ++j) mx8 = fmaxf(mx8, v[j]);
    float srt = mx8;
    sort64_desc_f32(srt, lane);
    float L32 = __int_as_float(__builtin_amdgcn_readlane(__float_as_int(srt), 31));

    // ---- survivor count + exclusive scan for LDS slots ----
    int cnt = 0;
    #pragma unroll
    for (int j = 0; j < 8; ++j) cnt += (v[j] >= L32) ? 1 : 0;
    u32 sincl = (u32)cnt;
    #pragma unroll
    for (int i = 1; i < 64; i <<= 1) {
        u32 t2 = __shfl_up(sincl, i);
        if (lane >= i) sincl += t2;
    }
    int sbase = (int)sincl - cnt;
    int S_tot = __builtin_amdgcn_readlane((int)sincl, 63);

    // ---- scatter survivor keys (valbits<<32 | 511-col): unique keys,
    // desc u64 order == np stable top-k order (value desc, col asc) ----
    int slot = sbase;
    #pragma unroll
    for (int j = 0; j < 8; ++j) {
        bool s = (v[j] >= L32);
        if (s) {
            int col = (j < 4) ? (l4 + j) : (256 + l4 + (j - 4));
            buf[wid][slot] = ((u64)__float_as_uint(v[j]) << 32) | (u32)(511 - col);
        }
        slot += s ? 1 : 0;
    }
    __threadfence_block();   // LDS visibility within the wave; NO __syncthreads

    u64 k;
    if (S_tot <= 64) {
        // common path (~99.98% of rows): one 64-wide u64 bitonic sort.
        // padding key 0 sorts below every real survivor (values > 0).
        k = (lane < S_tot) ? buf[wid][lane] : 0ull;
        sort64_desc_u64(k, lane);
    } else {
        // rare exact fallback: chunked sort + merge keep-top-64
        u64 cur = (lane < S_tot) ? buf[wid][lane] : 0ull;
        sort64_desc_u64(cur, lane);
        for (int base = 64; base < S_tot; base += 64) {
            u64 nxt = (base + lane < S_tot) ? buf[wid][base + lane] : 0ull;
            sort64_desc_u64(nxt, lane);
            u64 o = __shfl_xor(nxt, 63);           // nxt[63-lane]
            cur = (cur >= o) ? cur : o;            // top-64 of 128, bitonic
            #pragma unroll
            for (int j = 32; j > 0; j >>= 1) {     // descending cleanup
                u64 p = __shfl_xor(cur, j);
                bool keepMax = (lane & j) == 0;
                bool g = cur > p;
                cur = (keepMax == g) ? cur : p;
            }
        }
        k = cur;
    }
    // lane r now holds rank-r key (r < 32 are the selected top-32)

    // ---- coalesced stores: [orig 32 | selected 32] ----
    int src = (lane >= 32) ? (lane - 32) : 0;
    u64 kk = __shfl(k, src);
    const size_t ob = (size_t)row * Tgt;
    float oid, osc;
    if (lane < Ccand) {
        oid = (float)my_id;
        osc = my_s;
    } else {
        oid = (float)(int)(511 - (u32)(kk & 511ull));
        osc = __uint_as_float((u32)(kk >> 32));
    }
    out_ids[ob + lane]    = oid;
    out_scores[ob + lane] = osc;
}

extern "C" void kernel_launch(void* const* d_in, const int* in_sizes, int n_in,
                              void* d_out, int out_size, void* d_ws, size_t ws_size,
                              hipStream_t stream) {
    const int*   ids    = (const int*)d_in[0];
    const float* scores = (const float*)d_in[1];
    const float* cooc   = (const float*)d_in[2];
    int B = in_sizes[0] / Ccand;
    float* out_ids    = (float*)d_out;
    float* out_scores = out_ids + (size_t)B * Tgt;
    int blocks = (B + 3) / 4;
    hipLaunchKernelGGL(cooc_expand, dim3(blocks), dim3(256), 0, stream,
                       ids, scores, cooc, out_ids, out_scores, B);
}